// Round 9
// baseline (216519.482 us; speedup 1.0000x reference)
//
#include <hip/hip_runtime.h>
#include <stdint.h>
#include <math.h>

// Problem dims
#define Bn 256
#define Sn 512
#define En 256
#define Hn 256
#define Gn 1024            // 4*H
#define NSTEP 511          // S-1 decoder steps
#define MASK_VAL -100000.0

// Verified rounds 1-3,7-11: partitionable threefry + f64 compute -> absmax=0.
#define PARTITIONABLE 1

// ---------------------------------------------------------------- threefry
__device__ __forceinline__ uint32_t rotl32(uint32_t v, int d) {
  return (v << d) | (v >> (32 - d));
}

__device__ __forceinline__ void threefry2x32(uint32_t k0, uint32_t k1,
                                             uint32_t x0, uint32_t x1,
                                             uint32_t& o0, uint32_t& o1) {
  const uint32_t ks2 = k0 ^ k1 ^ 0x1BD11BDAu;
  x0 += k0; x1 += k1;
  x0 += x1; x1 = rotl32(x1, 13); x1 ^= x0;
  x0 += x1; x1 = rotl32(x1, 15); x1 ^= x0;
  x0 += x1; x1 = rotl32(x1, 26); x1 ^= x0;
  x0 += x1; x1 = rotl32(x1,  6); x1 ^= x0;
  x0 += k1; x1 += ks2 + 1u;
  x0 += x1; x1 = rotl32(x1, 17); x1 ^= x0;
  x0 += x1; x1 = rotl32(x1, 29); x1 ^= x0;
  x0 += x1; x1 = rotl32(x1, 16); x1 ^= x0;
  x0 += x1; x1 = rotl32(x1, 24); x1 ^= x0;
  x0 += ks2; x1 += k0 + 2u;
  x0 += x1; x1 = rotl32(x1, 13); x1 ^= x0;
  x0 += x1; x1 = rotl32(x1, 15); x1 ^= x0;
  x0 += x1; x1 = rotl32(x1, 26); x1 ^= x0;
  x0 += x1; x1 = rotl32(x1,  6); x1 ^= x0;
  x0 += k0; x1 += k1 + 3u;
  x0 += x1; x1 = rotl32(x1, 17); x1 ^= x0;
  x0 += x1; x1 = rotl32(x1, 29); x1 ^= x0;
  x0 += x1; x1 = rotl32(x1, 16); x1 ^= x0;
  x0 += x1; x1 = rotl32(x1, 24); x1 ^= x0;
  x0 += k1; x1 += ks2 + 4u;
  x0 += x1; x1 = rotl32(x1, 13); x1 ^= x0;
  x0 += x1; x1 = rotl32(x1, 15); x1 ^= x0;
  x0 += x1; x1 = rotl32(x1, 26); x1 ^= x0;
  x0 += x1; x1 = rotl32(x1,  6); x1 ^= x0;
  x0 += ks2; x1 += k0 + 5u;
  o0 = x0; o1 = x1;
}

__device__ __forceinline__ uint32_t random_word(uint32_t k0, uint32_t k1, uint32_t n) {
#if PARTITIONABLE
  uint32_t o0, o1;
  threefry2x32(k0, k1, 0u, n, o0, o1);
  return o0 ^ o1;
#else
  const uint32_t half = (Bn * Sn) / 2;
  uint32_t lane = (n < half) ? n : (n - half);
  uint32_t o0, o1;
  threefry2x32(k0, k1, lane, lane + half, o0, o1);
  return (n < half) ? o0 : o1;
#endif
}

__device__ __forceinline__ double sigmoid64(double x) {
  return 1.0 / (1.0 + exp(-x));
}

// ---------------------------------------------------------------- prep
__global__ __launch_bounds__(256) void k_wihe(const float* __restrict__ wemb,
                                              const float* __restrict__ wih,
                                              const float* __restrict__ bih,
                                              const float* __restrict__ bhh,
                                              double* __restrict__ wihe,
                                              double* __restrict__ bias) {
  int j = blockIdx.x * blockDim.x + threadIdx.x;
  if (j >= Gn) return;
  double a0 = 0.0, a1 = 0.0;
  for (int e = 0; e < En; ++e) {
    double w = (double)wih[j * En + e];
    a0 += (double)wemb[e] * w;
    a1 += (double)wemb[En + e] * w;
  }
  wihe[j] = a0;
  wihe[Gn + j] = a1;
  bias[j] = (double)bih[j] + (double)bhh[j];
}

__global__ __launch_bounds__(256) void k_keys(uint32_t* __restrict__ keys) {
  int j = blockIdx.x * blockDim.x + threadIdx.x;
  if (j >= NSTEP) return;
#if PARTITIONABLE
  uint32_t o0, o1;
  threefry2x32(0u, 1u, 0u, (uint32_t)j, o0, o1);
  keys[2 * j] = o0; keys[2 * j + 1] = o1;
#else
  uint32_t w[2];
  #pragma unroll
  for (int q = 0; q < 2; ++q) {
    uint32_t m = (uint32_t)(2 * j + q);
    uint32_t lane = (m < NSTEP) ? m : (m - NSTEP);
    uint32_t o0, o1;
    threefry2x32(0u, 1u, lane, lane + NSTEP, o0, o1);
    w[q] = (m < NSTEP) ? o0 : o1;
  }
  keys[2 * j] = w[0]; keys[2 * j + 1] = w[1];
#endif
}

// dst[k][j] = src[j][k]  (256x256 f32 transpose: Wq, Wref)
__global__ __launch_bounds__(256) void k_t32(const float* __restrict__ src,
                                             float* __restrict__ dst) {
  int idx = blockIdx.x * blockDim.x + threadIdx.x;
  int k = idx >> 8, j = idx & 255;
  dst[idx] = src[j * Hn + k];
}

// dst[k][j] = src[j][k]  (Whh: 1024 rows j, 256 cols k -> 256 x 1024)
__global__ __launch_bounds__(256) void k_t32w(const float* __restrict__ src,
                                              float* __restrict__ dst) {
  int idx = blockIdx.x * blockDim.x + threadIdx.x;   // 256*1024 elems
  int k = idx >> 10, j = idx & 1023;
  dst[idx] = src[j * Hn + k];
}

__global__ __launch_bounds__(256) void k_init(float* __restrict__ out) {
  int idx = blockIdx.x * blockDim.x + threadIdx.x;
  if (idx < Bn) out[Bn * NSTEP + idx * Sn] = 0.0f;   // indices[:,0] = START
}

// ---------------------------------------------------------------- main
// Block b owns batch row b end-to-end (zero cross-block communication).
// r20 = r16/r19 (verified best 27.26/27.39 ms, absmax 0) + refT register
// residency: each thread's phase-E refT slice is CONSTANT across all 511
// decoder steps, so half of it (c=0..7, 64 values) is loaded ONCE after
// the encoder into 64 individually-NAMED scalar floats (no array, no
// alloca -> structurally immune to the r13/r15 SROA-to-scratch trap;
// scalars like creg already span the whole kernel in registers).
// Phase E: fully-unrolled register half (c=0..7), then the proven
// st[8]-streamed half (c=8..15). Same values, same t-ascending
// accumulation order -> bit-identical outputs.
// VGPR: 56 + 64 ~= 120 <= 128 cap (1024 thr = 4 waves/SIMD).
// GATE: WRITE_SIZE must stay ~1.07e6 KB; ~100x jump = regalloc spill ->
// revert to r19.
// Ledger: r12 27.8 | r16/r19 27.3 BEST | r14 29.5 | r17 29.1 | r18 35.8 |
// r13/r15 171/251 (scratch). Locked lessons: scalar k-loop loads beat
// float4 clumps; refT stays [b][h][s] (wave-coalesced, lane=sE);
// staging arrays must be declared+consumed inside one loop body.
struct AttnS {
  double qpart[4][256];   // 8 KB
  double p2[2][512];      // 8 KB
  double sg[2][512];      // 8 KB  gumbel, double-buffered by t&1
  float2 qv2[256];        // 2 KB  {qf, v} fused
};

// 64 named scalar registers for the c=0..7 half of the refT slice
#define RDECL8(c) float rg##c##0, rg##c##1, rg##c##2, rg##c##3, \
                        rg##c##4, rg##c##5, rg##c##6, rg##c##7;
#define RLOAD8(c)                                     \
  rg##c##0 = rT[(size_t)((c) * 8 + 0) * Sn];          \
  rg##c##1 = rT[(size_t)((c) * 8 + 1) * Sn];          \
  rg##c##2 = rT[(size_t)((c) * 8 + 2) * Sn];          \
  rg##c##3 = rT[(size_t)((c) * 8 + 3) * Sn];          \
  rg##c##4 = rT[(size_t)((c) * 8 + 4) * Sn];          \
  rg##c##5 = rT[(size_t)((c) * 8 + 5) * Sn];          \
  rg##c##6 = rT[(size_t)((c) * 8 + 6) * Sn];          \
  rg##c##7 = rT[(size_t)((c) * 8 + 7) * Sn];
#define RCONS1(c, i)                                              \
  { float2 qv = at.qv2[ph * 128 + (c) * 8 + (i)];                 \
    la += (double)qv.y * (double)tanhf(qv.x + rg##c##i); }
#define RCONS8(c) RCONS1(c, 0) RCONS1(c, 1) RCONS1(c, 2) RCONS1(c, 3) \
                  RCONS1(c, 4) RCONS1(c, 5) RCONS1(c, 6) RCONS1(c, 7)

__global__ __launch_bounds__(1024, 4) void k_main(
    const float* __restrict__ inp,
    const double* __restrict__ wihe_e, const double* __restrict__ bias_e,
    const float* __restrict__ whhT_e,
    const double* __restrict__ wihe_d, const double* __restrict__ bias_d,
    const float* __restrict__ whhT_d,
    const float* __restrict__ wrefT, const float* __restrict__ wqT,
    const float* __restrict__ v,
    float* __restrict__ refT,
    const uint32_t* __restrict__ keys,
    float* __restrict__ out) {
  __shared__ __align__(16) double sh_h[Hn];   // current h (f64)
  __shared__ double sh_g[Gn];                 // transformed gates
  __shared__ AttnS at;

  const int b   = blockIdx.x;
  const int tid = threadIdx.x;
  const int w   = tid >> 6;
  const int l   = tid & 63;
  const int gsel = tid >> 8;      // 0:i 1:f 2:g 3:o (wave-uniform)

  // per-thread gate-row constants (j = tid)
  const double bj_e = bias_e[tid], w0e = wihe_e[tid], w1e = wihe_e[Gn + tid];
  const double bj_d = bias_d[tid], w0d = wihe_d[tid], w1d = wihe_d[Gn + tid];
  const float vreg = (tid < Hn) ? v[tid] : 0.0f;

  double creg = 0.0;              // c for unit u = tid (threads 0..255)
  if (tid < Hn) sh_h[tid] = 0.0;
  __syncthreads();

  const float* wcol_e = whhT_e + tid;
  const float* wcol_d = whhT_d + tid;
  const int part = tid >> 8, tcol = tid & 255;

  // ================================================================ encoder
  for (int s = 0; s < Sn; ++s) {
    // cell gates: exact k-ascending order (double2 reads, same math);
    // transform applied by the OWNING thread (same input -> same value)
    {
      double x0 = (double)inp[((size_t)b * Sn + s) * 2 + 0];
      double x1 = (double)inp[((size_t)b * Sn + s) * 2 + 1];
      double acc = bj_e + x0 * w0e + x1 * w1e;
      #pragma unroll 4
      for (int k = 0; k < Hn; k += 2) {
        double2 hv = *(const double2*)&sh_h[k];
        acc += hv.x * (double)wcol_e[(size_t)k << 10];
        acc += hv.y * (double)wcol_e[(size_t)(k + 1) << 10];
      }
      sh_g[tid] = (gsel == 2) ? tanh(acc) : sigmoid64(acc);
    }
    __syncthreads();                       // S1
    if (tid < Hn) {
      double ti = sh_g[tid];
      double tf = sh_g[256 + tid];
      double tg = sh_g[512 + tid];
      double to = sh_g[768 + tid];
      double cn = tf * creg + ti * tg;     // == sig(gf)*c + sig(gi)*tanh(gg)
      double hn = to * tanh(cn);
      creg = cn;
      sh_h[tid] = hn;
    }
    __syncthreads();                       // S2
    // refproj column s (verified split-k pattern, f64 h)
    {
      double racc = 0.0;
      #pragma unroll 8
      for (int i = 0; i < 64; ++i) {
        int k = part * 64 + i;
        racc += sh_h[k] * (double)wrefT[(size_t)k * Hn + tcol];
      }
      at.qpart[part][tcol] = racc;
    }
    __syncthreads();                       // S3
    if (tid < Hn) {
      double r = (at.qpart[0][tid] + at.qpart[1][tid]) +
                 (at.qpart[2][tid] + at.qpart[3][tid]);
      refT[((size_t)b * Hn + tid) * Sn + s] = (float)r;
    }
  }
  __syncthreads();   // refT fully written before register preload

  // ================================================================ decoder
  const int sE = tid & 511, ph = tid >> 9;
  const float* rT = refT + ((size_t)b * Hn + ph * 128) * Sn + sE;
  // one-time preload of the c=0..7 half into 64 named scalars
  RDECL8(0) RDECL8(1) RDECL8(2) RDECL8(3)
  RDECL8(4) RDECL8(5) RDECL8(6) RDECL8(7)
  RLOAD8(0) RLOAD8(1) RLOAD8(2) RLOAD8(3)
  RLOAD8(4) RLOAD8(5) RLOAD8(6) RLOAD8(7)

  int ch = 0;                               // START; uniform across threads
  unsigned mbits = (l == 0) ? 1u : 0u;      // bit k: s = l + 64k masked
  for (int t = 0; t < NSTEP; ++t) {
    const int par = t & 1;
    // A: cell (exact k-ascending order; double2 reads; uniform column scalar)
    {
      int col = __builtin_amdgcn_readfirstlane(ch);
      double x0 = (double)inp[((size_t)b * Sn + col) * 2 + 0];
      double x1 = (double)inp[((size_t)b * Sn + col) * 2 + 1];
      double acc = bj_d + x0 * w0d + x1 * w1d;
      #pragma unroll 4
      for (int k = 0; k < Hn; k += 2) {
        double2 hv = *(const double2*)&sh_h[k];
        acc += hv.x * (double)wcol_d[(size_t)k << 10];
        acc += hv.y * (double)wcol_d[(size_t)(k + 1) << 10];
      }
      sh_g[tid] = (gsel == 2) ? tanh(acc) : sigmoid64(acc);
    }
    __syncthreads();                       // S1
    // B: h-update (waves 0-3) || gumbel precompute (waves 8-15, else idle).
    if (tid < Hn) {
      double ti = sh_g[tid];
      double tf = sh_g[256 + tid];
      double tg = sh_g[512 + tid];
      double to = sh_g[768 + tid];
      double cn = tf * creg + ti * tg;
      double hn = to * tanh(cn);
      creg = cn;
      sh_h[tid] = hn;
    } else if (tid >= 512) {
      const uint32_t k0 = keys[2 * t], k1 = keys[2 * t + 1];
      int s0 = tid - 512;
      uint32_t wrd = random_word(k0, k1, (uint32_t)(b * Sn + s0));
      float uf = __uint_as_float((wrd >> 9) | 0x3f800000u) - 1.0f;
      uf = fmaxf(uf, 1.17549435e-38f);
      at.sg[par][s0] = -log(-log((double)uf));
    }
    __syncthreads();                       // S2
    // C: q-projection (r12 pattern)
    {
      double qa = 0.0;
      #pragma unroll 8
      for (int i = 0; i < 64; ++i) {
        int k = part * 64 + i;
        qa += sh_h[k] * (double)wqT[(size_t)k * Hn + tcol];
      }
      at.qpart[part][tcol] = qa;
    }
    __syncthreads();                       // S3
    if (tid < Hn) {
      double q = (at.qpart[0][tid] + at.qpart[1][tid]) +
                 (at.qpart[2][tid] + at.qpart[3][tid]);
      at.qv2[tid] = make_float2((float)q, vreg);
    }
    __syncthreads();                       // S4
    // E: logits (tanhf, f64 acc, t-ascending -- bit-identical order).
    // c=0..7 from registers (preloaded), c=8..15 streamed with st[8].
    {
      double la = 0.0;
      RCONS8(0) RCONS8(1) RCONS8(2) RCONS8(3)
      RCONS8(4) RCONS8(5) RCONS8(6) RCONS8(7)
      for (int c = 8; c < 16; ++c) {
        float st[8];
        #pragma unroll
        for (int i = 0; i < 8; ++i)
          st[i] = rT[(size_t)(c * 8 + i) * Sn];
        #pragma unroll
        for (int i = 0; i < 8; ++i) {
          int t2 = ph * 128 + c * 8 + i;
          float2 qv = at.qv2[t2];          // .x = qf[t2], .y = v[t2]
          la += (double)qv.y * (double)tanhf(qv.x + st[i]);
        }
      }
      at.p2[ph][sE] = la;
    }
    __syncthreads();                       // S5
    // F: inline sampling (register masks), bit-identical compare sequence
    double slv[8];
    {
      #pragma unroll
      for (int k = 0; k < 8; ++k) {
        int s2 = l + k * 64;
        slv[k] = (mbits >> k) & 1u ? (double)MASK_VAL
                                   : (at.p2[0][s2] + at.p2[1][s2]);
      }
      double bz = slv[0] + at.sg[par][l];
      int bi = l;
      #pragma unroll
      for (int k = 1; k < 8; ++k) {
        int s2 = l + k * 64;
        double z2 = slv[k] + at.sg[par][s2];
        if (z2 > bz || (z2 == bz && s2 < bi)) { bz = z2; bi = s2; }
      }
      #pragma unroll
      for (int m = 32; m >= 1; m >>= 1) {
        double oz = __shfl_xor(bz, m);
        int    oi = __shfl_xor(bi, m);
        if (oz > bz || (oz == bz && oi < bi)) { bz = oz; bi = oi; }
      }
      ch = bi;
    }
    // logsumexp (wave 1 only) + output writes
    if (w == 1) {
      double bm = slv[0];
      #pragma unroll
      for (int k = 1; k < 8; ++k) bm = fmax(bm, slv[k]);
      #pragma unroll
      for (int m = 32; m >= 1; m >>= 1) bm = fmax(bm, __shfl_xor(bm, m));
      double ps = 0.0;
      #pragma unroll
      for (int k = 0; k < 8; ++k) ps += exp(slv[k] - bm);
      #pragma unroll
      for (int m = 32; m >= 1; m >>= 1) ps += __shfl_xor(ps, m);
      if (l == 0) {
        double lse = bm + log(ps);
        double slch = at.p2[0][ch] + at.p2[1][ch];   // ch is never masked
        double lp = slch - lse;
        out[(size_t)b * NSTEP + t] = (float)lp;
        out[(size_t)Bn * NSTEP + (size_t)b * Sn + (t + 1)] = (float)ch;
      }
    }
    // register mask update (every thread, every wave)
    if ((ch & 63) == l) mbits |= 1u << (ch >> 6);
    // no trailing barrier: next step's S1..S5 separate p2/sg/qv2 hazards;
    // sg double-buffer isolates the next gumbel write from this step's reads
  }
}

// ---------------------------------------------------------------- launch
extern "C" void kernel_launch(void* const* d_in, const int* in_sizes, int n_in,
                              void* d_out, int out_size, void* d_ws, size_t ws_size,
                              hipStream_t stream) {
  const float* inp  = (const float*)d_in[0];
  const float* wemb = (const float*)d_in[1];
  const float* eWih = (const float*)d_in[2];
  const float* eWhh = (const float*)d_in[3];
  const float* ebih = (const float*)d_in[4];
  const float* ebhh = (const float*)d_in[5];
  const float* dWih = (const float*)d_in[6];
  const float* dWhh = (const float*)d_in[7];
  const float* dbih = (const float*)d_in[8];
  const float* dbhh = (const float*)d_in[9];
  const float* Wq   = (const float*)d_in[10];
  const float* Wref = (const float*)d_in[11];
  const float* v    = (const float*)d_in[12];
  float* out = (float*)d_out;

  char* ws = (char*)d_ws;
  size_t off = 0;
  auto alloc = [&](size_t bytes) -> void* {
    void* p = (void*)(ws + off);
    off += (bytes + 255) & ~(size_t)255;
    return p;
  };
  // total ~137 MB (proven workspace level)
  float*    refT   = (float*)   alloc((size_t)Bn * Sn * Hn * sizeof(float));   // 134 MB
  float*    whhT_e = (float*)   alloc((size_t)Hn * Gn * sizeof(float));        // 1 MB
  float*    whhT_d = (float*)   alloc((size_t)Hn * Gn * sizeof(float));        // 1 MB
  float*    wqT    = (float*)   alloc((size_t)Hn * Hn * sizeof(float));
  float*    wrefT  = (float*)   alloc((size_t)Hn * Hn * sizeof(float));
  double*   wihe_e = (double*)  alloc(2 * Gn * sizeof(double));
  double*   wihe_d = (double*)  alloc(2 * Gn * sizeof(double));
  double*   bias_e = (double*)  alloc(Gn * sizeof(double));
  double*   bias_d = (double*)  alloc(Gn * sizeof(double));
  uint32_t* keys   = (uint32_t*)alloc(2 * NSTEP * sizeof(uint32_t));
  (void)ws_size; (void)in_sizes; (void)n_in; (void)out_size;

  k_wihe<<<Gn / 256, 256, 0, stream>>>(wemb, eWih, ebih, ebhh, wihe_e, bias_e);
  k_wihe<<<Gn / 256, 256, 0, stream>>>(wemb, dWih, dbih, dbhh, wihe_d, bias_d);
  k_keys<<<2, 256, 0, stream>>>(keys);
  k_t32<<<(Hn * Hn) / 256, 256, 0, stream>>>(Wq, wqT);
  k_t32<<<(Hn * Hn) / 256, 256, 0, stream>>>(Wref, wrefT);
  k_t32w<<<(Hn * Gn) / 256, 256, 0, stream>>>(eWhh, whhT_e);
  k_t32w<<<(Hn * Gn) / 256, 256, 0, stream>>>(dWhh, whhT_d);
  k_init<<<1, 256, 0, stream>>>(out);

  k_main<<<Bn, 1024, 0, stream>>>(
      inp, wihe_e, bias_e, whhT_e, wihe_d, bias_d, whhT_d,
      wrefT, wqT, v, refT, keys, out);
}

// Round 10
// 27302.899 us; speedup vs baseline: 7.9303x; 7.9303x over previous
//
#include <hip/hip_runtime.h>
#include <stdint.h>
#include <math.h>

// Problem dims
#define Bn 256
#define Sn 512
#define En 256
#define Hn 256
#define Gn 1024            // 4*H
#define NSTEP 511          // S-1 decoder steps
#define MASK_VAL -100000.0

// Verified rounds 1-3,7-11: partitionable threefry + f64 compute -> absmax=0.
#define PARTITIONABLE 1

// ---------------------------------------------------------------- threefry
__device__ __forceinline__ uint32_t rotl32(uint32_t v, int d) {
  return (v << d) | (v >> (32 - d));
}

__device__ __forceinline__ void threefry2x32(uint32_t k0, uint32_t k1,
                                             uint32_t x0, uint32_t x1,
                                             uint32_t& o0, uint32_t& o1) {
  const uint32_t ks2 = k0 ^ k1 ^ 0x1BD11BDAu;
  x0 += k0; x1 += k1;
  x0 += x1; x1 = rotl32(x1, 13); x1 ^= x0;
  x0 += x1; x1 = rotl32(x1, 15); x1 ^= x0;
  x0 += x1; x1 = rotl32(x1, 26); x1 ^= x0;
  x0 += x1; x1 = rotl32(x1,  6); x1 ^= x0;
  x0 += k1; x1 += ks2 + 1u;
  x0 += x1; x1 = rotl32(x1, 17); x1 ^= x0;
  x0 += x1; x1 = rotl32(x1, 29); x1 ^= x0;
  x0 += x1; x1 = rotl32(x1, 16); x1 ^= x0;
  x0 += x1; x1 = rotl32(x1, 24); x1 ^= x0;
  x0 += ks2; x1 += k0 + 2u;
  x0 += x1; x1 = rotl32(x1, 13); x1 ^= x0;
  x0 += x1; x1 = rotl32(x1, 15); x1 ^= x0;
  x0 += x1; x1 = rotl32(x1, 26); x1 ^= x0;
  x0 += x1; x1 = rotl32(x1,  6); x1 ^= x0;
  x0 += k0; x1 += k1 + 3u;
  x0 += x1; x1 = rotl32(x1, 17); x1 ^= x0;
  x0 += x1; x1 = rotl32(x1, 29); x1 ^= x0;
  x0 += x1; x1 = rotl32(x1, 16); x1 ^= x0;
  x0 += x1; x1 = rotl32(x1, 24); x1 ^= x0;
  x0 += k1; x1 += ks2 + 4u;
  x0 += x1; x1 = rotl32(x1, 13); x1 ^= x0;
  x0 += x1; x1 = rotl32(x1, 15); x1 ^= x0;
  x0 += x1; x1 = rotl32(x1, 26); x1 ^= x0;
  x0 += x1; x1 = rotl32(x1,  6); x1 ^= x0;
  x0 += ks2; x1 += k0 + 5u;
  o0 = x0; o1 = x1;
}

__device__ __forceinline__ uint32_t random_word(uint32_t k0, uint32_t k1, uint32_t n) {
#if PARTITIONABLE
  uint32_t o0, o1;
  threefry2x32(k0, k1, 0u, n, o0, o1);
  return o0 ^ o1;
#else
  const uint32_t half = (Bn * Sn) / 2;
  uint32_t lane = (n < half) ? n : (n - half);
  uint32_t o0, o1;
  threefry2x32(k0, k1, lane, lane + half, o0, o1);
  return (n < half) ? o0 : o1;
#endif
}

__device__ __forceinline__ double sigmoid64(double x) {
  return 1.0 / (1.0 + exp(-x));
}

// ---------------------------------------------------------------- prep
__global__ __launch_bounds__(256) void k_wihe(const float* __restrict__ wemb,
                                              const float* __restrict__ wih,
                                              const float* __restrict__ bih,
                                              const float* __restrict__ bhh,
                                              double* __restrict__ wihe,
                                              double* __restrict__ bias) {
  int j = blockIdx.x * blockDim.x + threadIdx.x;
  if (j >= Gn) return;
  double a0 = 0.0, a1 = 0.0;
  for (int e = 0; e < En; ++e) {
    double w = (double)wih[j * En + e];
    a0 += (double)wemb[e] * w;
    a1 += (double)wemb[En + e] * w;
  }
  wihe[j] = a0;
  wihe[Gn + j] = a1;
  bias[j] = (double)bih[j] + (double)bhh[j];
}

__global__ __launch_bounds__(256) void k_keys(uint32_t* __restrict__ keys) {
  int j = blockIdx.x * blockDim.x + threadIdx.x;
  if (j >= NSTEP) return;
#if PARTITIONABLE
  uint32_t o0, o1;
  threefry2x32(0u, 1u, 0u, (uint32_t)j, o0, o1);
  keys[2 * j] = o0; keys[2 * j + 1] = o1;
#else
  uint32_t w[2];
  #pragma unroll
  for (int q = 0; q < 2; ++q) {
    uint32_t m = (uint32_t)(2 * j + q);
    uint32_t lane = (m < NSTEP) ? m : (m - NSTEP);
    uint32_t o0, o1;
    threefry2x32(0u, 1u, lane, lane + NSTEP, o0, o1);
    w[q] = (m < NSTEP) ? o0 : o1;
  }
  keys[2 * j] = w[0]; keys[2 * j + 1] = w[1];
#endif
}

// dst[k][j] = src[j][k]  (256x256 f32 transpose: Wq, Wref)
__global__ __launch_bounds__(256) void k_t32(const float* __restrict__ src,
                                             float* __restrict__ dst) {
  int idx = blockIdx.x * blockDim.x + threadIdx.x;
  int k = idx >> 8, j = idx & 255;
  dst[idx] = src[j * Hn + k];
}

// dst[k][j] = src[j][k]  (Whh: 1024 rows j, 256 cols k -> 256 x 1024)
__global__ __launch_bounds__(256) void k_t32w(const float* __restrict__ src,
                                              float* __restrict__ dst) {
  int idx = blockIdx.x * blockDim.x + threadIdx.x;   // 256*1024 elems
  int k = idx >> 10, j = idx & 1023;
  dst[idx] = src[j * Hn + k];
}

__global__ __launch_bounds__(256) void k_init(float* __restrict__ out) {
  int idx = blockIdx.x * blockDim.x + threadIdx.x;
  if (idx < Bn) out[Bn * NSTEP + idx * Sn] = 0.0f;   // indices[:,0] = START
}

// ---------------------------------------------------------------- main
// Block b owns batch row b end-to-end (zero cross-block communication).
// r21 = REVERT to r19/r16 verbatim (verified best: 27.26/27.39 ms, absmax 0,
// VGPR 56, zero spill). r16 = r12 + gumbel offloaded to idle waves (phase B)
// + qf/v fused into one float2 LDS read (phase E).
// Experiment ledger (all absmax 0):
//   r12 27.8 | r16 27.26 / r19 27.39 BEST | r14 29.5 (packed-f4+enc-fold) |
//   r17 29.1 (refT [b][s][h]: broke wave-coalescing, FETCH +24%) |
//   r18 35.8 (packed-f4 + E-unroll2: load-clumping, VALUBusy 58->38) |
//   r13/r15/r20 171/251/216 (cross-phase register state -> SCRATCH).
// Final compiler law (3x measured): the 1024-thread block REQUIRES 4
// waves/SIMD residency -> hard 128-VGPR cap; phase A's pipelined loads use
// ~100 transiently, so NO meaningful state can live across barriers beyond
// the ~56-VGPR working set -- arrays, macro pipelines, and even 64 named
// scalars all get spilled (WRITE_SIZE 1e6 -> ~2e8 KB signature).
// Other locked lessons:
//  - scalar k-loop loads (256 independent) beat float4 clumps here.
//  - refT stays [b][h][s]: phase-E loads are wave-coalesced (lane = sE).
//  - staging arrays must be declared AND consumed inside one loop body.
//  - VALU-issue floor ~16 ms; busy time is already there (58% x 27.3).
struct AttnS {
  double qpart[4][256];   // 8 KB
  double p2[2][512];      // 8 KB
  double sg[2][512];      // 8 KB  gumbel, double-buffered by t&1
  float2 qv2[256];        // 2 KB  {qf, v} fused
};

__global__ __launch_bounds__(1024, 4) void k_main(
    const float* __restrict__ inp,
    const double* __restrict__ wihe_e, const double* __restrict__ bias_e,
    const float* __restrict__ whhT_e,
    const double* __restrict__ wihe_d, const double* __restrict__ bias_d,
    const float* __restrict__ whhT_d,
    const float* __restrict__ wrefT, const float* __restrict__ wqT,
    const float* __restrict__ v,
    float* __restrict__ refT,
    const uint32_t* __restrict__ keys,
    float* __restrict__ out) {
  __shared__ __align__(16) double sh_h[Hn];   // current h (f64)
  __shared__ double sh_g[Gn];                 // transformed gates
  __shared__ AttnS at;

  const int b   = blockIdx.x;
  const int tid = threadIdx.x;
  const int w   = tid >> 6;
  const int l   = tid & 63;
  const int gsel = tid >> 8;      // 0:i 1:f 2:g 3:o (wave-uniform)

  // per-thread gate-row constants (j = tid)
  const double bj_e = bias_e[tid], w0e = wihe_e[tid], w1e = wihe_e[Gn + tid];
  const double bj_d = bias_d[tid], w0d = wihe_d[tid], w1d = wihe_d[Gn + tid];
  const float vreg = (tid < Hn) ? v[tid] : 0.0f;

  double creg = 0.0;              // c for unit u = tid (threads 0..255)
  if (tid < Hn) sh_h[tid] = 0.0;
  __syncthreads();

  const float* wcol_e = whhT_e + tid;
  const float* wcol_d = whhT_d + tid;
  const int part = tid >> 8, tcol = tid & 255;

  // ================================================================ encoder
  for (int s = 0; s < Sn; ++s) {
    // cell gates: exact k-ascending order (double2 reads, same math);
    // transform applied by the OWNING thread (same input -> same value)
    {
      double x0 = (double)inp[((size_t)b * Sn + s) * 2 + 0];
      double x1 = (double)inp[((size_t)b * Sn + s) * 2 + 1];
      double acc = bj_e + x0 * w0e + x1 * w1e;
      #pragma unroll 4
      for (int k = 0; k < Hn; k += 2) {
        double2 hv = *(const double2*)&sh_h[k];
        acc += hv.x * (double)wcol_e[(size_t)k << 10];
        acc += hv.y * (double)wcol_e[(size_t)(k + 1) << 10];
      }
      sh_g[tid] = (gsel == 2) ? tanh(acc) : sigmoid64(acc);
    }
    __syncthreads();                       // S1
    if (tid < Hn) {
      double ti = sh_g[tid];
      double tf = sh_g[256 + tid];
      double tg = sh_g[512 + tid];
      double to = sh_g[768 + tid];
      double cn = tf * creg + ti * tg;     // == sig(gf)*c + sig(gi)*tanh(gg)
      double hn = to * tanh(cn);
      creg = cn;
      sh_h[tid] = hn;
    }
    __syncthreads();                       // S2
    // refproj column s (verified split-k pattern, f64 h)
    {
      double racc = 0.0;
      #pragma unroll 8
      for (int i = 0; i < 64; ++i) {
        int k = part * 64 + i;
        racc += sh_h[k] * (double)wrefT[(size_t)k * Hn + tcol];
      }
      at.qpart[part][tcol] = racc;
    }
    __syncthreads();                       // S3
    if (tid < Hn) {
      double r = (at.qpart[0][tid] + at.qpart[1][tid]) +
                 (at.qpart[2][tid] + at.qpart[3][tid]);
      refT[((size_t)b * Hn + tid) * Sn + s] = (float)r;
    }
  }

  // ================================================================ decoder
  int ch = 0;                               // START; uniform across threads
  unsigned mbits = (l == 0) ? 1u : 0u;      // bit k: s = l + 64k masked
  for (int t = 0; t < NSTEP; ++t) {
    const int par = t & 1;
    // A: cell (exact k-ascending order; double2 reads; uniform column scalar)
    {
      int col = __builtin_amdgcn_readfirstlane(ch);
      double x0 = (double)inp[((size_t)b * Sn + col) * 2 + 0];
      double x1 = (double)inp[((size_t)b * Sn + col) * 2 + 1];
      double acc = bj_d + x0 * w0d + x1 * w1d;
      #pragma unroll 4
      for (int k = 0; k < Hn; k += 2) {
        double2 hv = *(const double2*)&sh_h[k];
        acc += hv.x * (double)wcol_d[(size_t)k << 10];
        acc += hv.y * (double)wcol_d[(size_t)(k + 1) << 10];
      }
      sh_g[tid] = (gsel == 2) ? tanh(acc) : sigmoid64(acc);
    }
    __syncthreads();                       // S1
    // B: h-update (waves 0-3) || gumbel precompute (waves 8-15, else idle).
    // sg double-buffer isolates this write from step t-1's sampling reads
    // (sampling t-1 reads sg[par^1]; S1 separates it from this phase anyway).
    if (tid < Hn) {
      double ti = sh_g[tid];
      double tf = sh_g[256 + tid];
      double tg = sh_g[512 + tid];
      double to = sh_g[768 + tid];
      double cn = tf * creg + ti * tg;
      double hn = to * tanh(cn);
      creg = cn;
      sh_h[tid] = hn;
    } else if (tid >= 512) {
      const uint32_t k0 = keys[2 * t], k1 = keys[2 * t + 1];
      int s0 = tid - 512;
      uint32_t wrd = random_word(k0, k1, (uint32_t)(b * Sn + s0));
      float uf = __uint_as_float((wrd >> 9) | 0x3f800000u) - 1.0f;
      uf = fmaxf(uf, 1.17549435e-38f);
      at.sg[par][s0] = -log(-log((double)uf));
    }
    __syncthreads();                       // S2
    // C: q-projection (r12 pattern)
    {
      double qa = 0.0;
      #pragma unroll 8
      for (int i = 0; i < 64; ++i) {
        int k = part * 64 + i;
        qa += sh_h[k] * (double)wqT[(size_t)k * Hn + tcol];
      }
      at.qpart[part][tcol] = qa;
    }
    __syncthreads();                       // S3
    if (tid < Hn) {
      double q = (at.qpart[0][tid] + at.qpart[1][tid]) +
                 (at.qpart[2][tid] + at.qpart[3][tid]);
      at.qv2[tid] = make_float2((float)q, vreg);
    }
    __syncthreads();                       // S4
    // E: logits: r12 exact (tanhf, f64 acc, t-ascending, 8-deep staging
    // declared INSIDE the c loop -- the only staging pattern this compiler
    // keeps in registers). qf+v as one float2 read.
    {
      const int sE = tid & 511, ph = tid >> 9;
      const float* rT = refT + ((size_t)b * Hn + ph * 128) * Sn + sE;
      double la = 0.0;
      for (int c = 0; c < 16; ++c) {
        float st[8];
        #pragma unroll
        for (int i = 0; i < 8; ++i)
          st[i] = rT[(size_t)(c * 8 + i) * Sn];
        #pragma unroll
        for (int i = 0; i < 8; ++i) {
          int t2 = ph * 128 + c * 8 + i;
          float2 qv = at.qv2[t2];          // .x = qf[t2], .y = v[t2]
          la += (double)qv.y * (double)tanhf(qv.x + st[i]);
        }
      }
      at.p2[ph][sE] = la;
    }
    __syncthreads();                       // S5
    // F: inline sampling (register masks), bit-identical compare sequence
    double slv[8];
    {
      #pragma unroll
      for (int k = 0; k < 8; ++k) {
        int s2 = l + k * 64;
        slv[k] = (mbits >> k) & 1u ? (double)MASK_VAL
                                   : (at.p2[0][s2] + at.p2[1][s2]);
      }
      double bz = slv[0] + at.sg[par][l];
      int bi = l;
      #pragma unroll
      for (int k = 1; k < 8; ++k) {
        int s2 = l + k * 64;
        double z2 = slv[k] + at.sg[par][s2];
        if (z2 > bz || (z2 == bz && s2 < bi)) { bz = z2; bi = s2; }
      }
      #pragma unroll
      for (int m = 32; m >= 1; m >>= 1) {
        double oz = __shfl_xor(bz, m);
        int    oi = __shfl_xor(bi, m);
        if (oz > bz || (oz == bz && oi < bi)) { bz = oz; bi = oi; }
      }
      ch = bi;
    }
    // logsumexp (wave 1 only) + output writes
    if (w == 1) {
      double bm = slv[0];
      #pragma unroll
      for (int k = 1; k < 8; ++k) bm = fmax(bm, slv[k]);
      #pragma unroll
      for (int m = 32; m >= 1; m >>= 1) bm = fmax(bm, __shfl_xor(bm, m));
      double ps = 0.0;
      #pragma unroll
      for (int k = 0; k < 8; ++k) ps += exp(slv[k] - bm);
      #pragma unroll
      for (int m = 32; m >= 1; m >>= 1) ps += __shfl_xor(ps, m);
      if (l == 0) {
        double lse = bm + log(ps);
        double slch = at.p2[0][ch] + at.p2[1][ch];   // ch is never masked
        double lp = slch - lse;
        out[(size_t)b * NSTEP + t] = (float)lp;
        out[(size_t)Bn * NSTEP + (size_t)b * Sn + (t + 1)] = (float)ch;
      }
    }
    // register mask update (every thread, every wave)
    if ((ch & 63) == l) mbits |= 1u << (ch >> 6);
    // no trailing barrier: next step's S1..S5 separate p2/sg/qv2 hazards;
    // sg double-buffer isolates the next gumbel write from this step's reads
  }
}

// ---------------------------------------------------------------- launch
extern "C" void kernel_launch(void* const* d_in, const int* in_sizes, int n_in,
                              void* d_out, int out_size, void* d_ws, size_t ws_size,
                              hipStream_t stream) {
  const float* inp  = (const float*)d_in[0];
  const float* wemb = (const float*)d_in[1];
  const float* eWih = (const float*)d_in[2];
  const float* eWhh = (const float*)d_in[3];
  const float* ebih = (const float*)d_in[4];
  const float* ebhh = (const float*)d_in[5];
  const float* dWih = (const float*)d_in[6];
  const float* dWhh = (const float*)d_in[7];
  const float* dbih = (const float*)d_in[8];
  const float* dbhh = (const float*)d_in[9];
  const float* Wq   = (const float*)d_in[10];
  const float* Wref = (const float*)d_in[11];
  const float* v    = (const float*)d_in[12];
  float* out = (float*)d_out;

  char* ws = (char*)d_ws;
  size_t off = 0;
  auto alloc = [&](size_t bytes) -> void* {
    void* p = (void*)(ws + off);
    off += (bytes + 255) & ~(size_t)255;
    return p;
  };
  // total ~137 MB (proven workspace level)
  float*    refT   = (float*)   alloc((size_t)Bn * Sn * Hn * sizeof(float));   // 134 MB
  float*    whhT_e = (float*)   alloc((size_t)Hn * Gn * sizeof(float));        // 1 MB
  float*    whhT_d = (float*)   alloc((size_t)Hn * Gn * sizeof(float));        // 1 MB
  float*    wqT    = (float*)   alloc((size_t)Hn * Hn * sizeof(float));
  float*    wrefT  = (float*)   alloc((size_t)Hn * Hn * sizeof(float));
  double*   wihe_e = (double*)  alloc(2 * Gn * sizeof(double));
  double*   wihe_d = (double*)  alloc(2 * Gn * sizeof(double));
  double*   bias_e = (double*)  alloc(Gn * sizeof(double));
  double*   bias_d = (double*)  alloc(Gn * sizeof(double));
  uint32_t* keys   = (uint32_t*)alloc(2 * NSTEP * sizeof(uint32_t));
  (void)ws_size; (void)in_sizes; (void)n_in; (void)out_size;

  k_wihe<<<Gn / 256, 256, 0, stream>>>(wemb, eWih, ebih, ebhh, wihe_e, bias_e);
  k_wihe<<<Gn / 256, 256, 0, stream>>>(wemb, dWih, dbih, dbhh, wihe_d, bias_d);
  k_keys<<<2, 256, 0, stream>>>(keys);
  k_t32<<<(Hn * Hn) / 256, 256, 0, stream>>>(Wq, wqT);
  k_t32<<<(Hn * Hn) / 256, 256, 0, stream>>>(Wref, wrefT);
  k_t32w<<<(Hn * Gn) / 256, 256, 0, stream>>>(eWhh, whhT_e);
  k_t32w<<<(Hn * Gn) / 256, 256, 0, stream>>>(dWhh, whhT_d);
  k_init<<<1, 256, 0, stream>>>(out);

  k_main<<<Bn, 1024, 0, stream>>>(
      inp, wihe_e, bias_e, whhT_e, wihe_d, bias_d, whhT_d,
      wrefT, wqT, v, refT, keys, out);
}